// Round 1
// baseline (571.643 us; speedup 1.0000x reference)
//
#include <hip/hip_runtime.h>
#include <cstdint>

#define N_ANCH 8400
#define CBLK 132              // ceil(8400/64)
#define SCORE_THR 0.5f

typedef unsigned long long u64;
typedef unsigned int u32;

// Sort key: ascending sort == (valid score descending, then index ascending,
// invalid last by index ascending) — exactly matches
// argsort(-where(valid, s, -inf)) with stable ties.
__device__ __forceinline__ u64 sort_key(float s, int idx) {
  u32 k32 = (s >= SCORE_THR) ? ~__float_as_uint(s) : 0xFFFFFFFFu;
  return ((u64)k32 << 32) | (u32)idx;
}

// One 64-lane wave per anchor: rank = #{keys smaller}, then scatter
// decoded box + score into sorted position.
__global__ void __launch_bounds__(256) rank_kernel(const float* __restrict__ raw,
                                                   float4* __restrict__ sbox,
                                                   float* __restrict__ sscore) {
  #pragma clang fp contract(off)
  int tid = blockIdx.x * 256 + threadIdx.x;
  int row = tid >> 6, lane = tid & 63;
  if (row >= N_ANCH) return;
  float si = raw[4 * N_ANCH + row];
  u64 ki = sort_key(si, row);
  int cnt = 0;
  for (int j = lane; j < N_ANCH; j += 64) {
    float sj = raw[4 * N_ANCH + j];
    cnt += (sort_key(sj, j) < ki) ? 1 : 0;
  }
  #pragma unroll
  for (int d = 1; d < 64; d <<= 1) cnt += __shfl_xor(cnt, d, 64);
  if (lane == 0) {
    float cx = raw[row], cy = raw[N_ANCH + row];
    float w = raw[2 * N_ANCH + row], h = raw[3 * N_ANCH + row];
    float hw = w * 0.5f, hh = h * 0.5f;
    sbox[cnt] = make_float4(cx - hw, cy - hh, cx + hw, cy + hh);
    sscore[cnt] = si;
  }
}

// Suppression bitmask over sorted boxes: mask[i*CBLK+cb] bit jj set iff
// j = cb*64+jj satisfies j>i, j<N, iou(i,j) > 0.5.  Upper triangle only.
__global__ void __launch_bounds__(64) mask_kernel(const float4* __restrict__ sbox,
                                                  u64* __restrict__ mask) {
  #pragma clang fp contract(off)
  int cb = blockIdx.x, rb = blockIdx.y;
  if (cb < rb) return;                    // j-blocks strictly before i-block: never needed
  int t = threadIdx.x;
  __shared__ float4 cbox[64];
  __shared__ float carea[64];
  int j0 = cb * 64;
  int j = j0 + t;
  float4 bj = (j < N_ANCH) ? sbox[j] : make_float4(0.f, 0.f, 0.f, 0.f);
  cbox[t] = bj;
  carea[t] = (bj.z - bj.x) * (bj.w - bj.y);
  __syncthreads();
  int i = rb * 64 + t;
  if (i >= N_ANCH) return;
  float4 bi = sbox[i];
  float ai = (bi.z - bi.x) * (bi.w - bi.y);
  u64 word = 0;
  for (int jj = 0; jj < 64; ++jj) {
    int jg = j0 + jj;
    if (jg <= i || jg >= N_ANCH) continue;
    float4 bb = cbox[jj];
    float ltx = fmaxf(bi.x, bb.x), lty = fmaxf(bi.y, bb.y);
    float rbx = fminf(bi.z, bb.z), rby = fminf(bi.w, bb.w);
    float wx = fmaxf(rbx - ltx, 0.f), wy = fmaxf(rby - lty, 0.f);
    float inter = wx * wy;
    float uni = (ai + carea[jj]) - inter;      // same op order as reference
    float iou = inter / fmaxf(uni, 1e-9f);     // IEEE div, matches numpy
    if (iou > 0.5f) word |= (1ull << jj);
  }
  mask[(u64)i * CBLK + cb] = word;
}

// Single block: sequential greedy NMS over 132 row-blocks, then fused output.
__global__ void __launch_bounds__(256) nms_kernel(const float4* __restrict__ sbox,
                                                  const float* __restrict__ sscore,
                                                  const u64* __restrict__ mask,
                                                  float* __restrict__ out) {
  __shared__ u64 lds_m[64];
  __shared__ u64 lds_keep[CBLK];
  __shared__ u64 lds_cur;
  __shared__ u64 lds_valid;
  int t = threadIdx.x;
  u64 remv = 0;                 // thread t (<132) owns removed-word of col-block t

  for (int b = 0; b < CBLK; ++b) {
    float s0 = sscore[b * 64];                  // max score in block (desc order)
    if (!(s0 >= SCORE_THR)) {                   // whole block invalid -> keep=0
      if (t == 0) lds_keep[b] = 0;
      continue;                                  // uniform branch, no barrier inside
    }
    if (t < 64) {                                // wave 0 stages intra-block data
      int r = b * 64 + t;
      lds_m[t] = (r < N_ANCH) ? mask[(u64)r * CBLK + b] : 0;
      u64 bal = __ballot(r < N_ANCH && sscore[r] >= SCORE_THR);
      if (t == 0) lds_valid = bal;
    }
    if (t == b) lds_cur = remv;                  // starting removed bits for this block
    __syncthreads();
    if (t == 0) {                                // serial greedy within block
      u64 act = lds_valid & ~lds_cur;
      u64 keep = 0;
      while (act) {
        int l = __builtin_ctzll(act);
        keep |= (1ull << l);
        act &= ~(1ull << l);
        act &= ~lds_m[l];                        // suppressed by row l (bits > l only)
      }
      lds_keep[b] = keep;
    }
    __syncthreads();
    u64 kw = lds_keep[b];
    if (t > b && t < CBLK && kw) {               // propagate suppression to later blocks
      u64 k = kw;
      while (k) {
        int l = __builtin_ctzll(k);
        k &= k - 1;
        remv |= mask[(u64)(b * 64 + l) * CBLK + t];
      }
    }
  }
  __syncthreads();
  const float* sb = (const float*)sbox;
  for (int e = t; e < N_ANCH * 5; e += 256) {
    int r = e / 5, f = e - 5 * r;
    float v = 0.f;
    if ((lds_keep[r >> 6] >> (r & 63)) & 1ull) {
      v = (f == 4) ? sscore[r] : sb[r * 4 + f];
    }
    out[e] = v;
  }
}

extern "C" void kernel_launch(void* const* d_in, const int* in_sizes, int n_in,
                              void* d_out, int out_size, void* d_ws, size_t ws_size,
                              hipStream_t stream) {
  const float* raw = (const float*)d_in[0];
  float* out = (float*)d_out;
  char* ws = (char*)d_ws;
  // ws layout: sbox (8448*16 B) | sscore (8448*4 B) | mask (8400*132*8 B) ≈ 9.04 MB
  float4* sbox = (float4*)ws;
  float* sscore = (float*)(ws + 8448 * 16);
  u64* mask = (u64*)(ws + 8448 * 16 + 8448 * 4);

  rank_kernel<<<2100, 256, 0, stream>>>(raw, sbox, sscore);
  mask_kernel<<<dim3(CBLK, CBLK), 64, 0, stream>>>(sbox, mask);
  nms_kernel<<<1, 256, 0, stream>>>(sbox, sscore, mask, out);
}

// Round 2
// 289.007 us; speedup vs baseline: 1.9780x; 1.9780x over previous
//
#include <hip/hip_runtime.h>
#include <cstdint>

#define N_ANCH 8400
#define CBLK 132              // ceil(8400/64)
#define SCORE_THR 0.5f

typedef unsigned long long u64;
typedef unsigned int u32;
typedef unsigned short u16;

// Sort key: ascending sort == (valid score descending, then index ascending,
// invalid last by index ascending) — exactly matches
// argsort(-where(valid, s, -inf)) with stable ties.
__device__ __forceinline__ u64 sort_key(float s, int idx) {
  u32 k32 = (s >= SCORE_THR) ? ~__float_as_uint(s) : 0xFFFFFFFFu;
  return ((u64)k32 << 32) | (u32)idx;
}

__device__ __forceinline__ u64 shfl_u64(u64 v, int src) {
  u32 lo = __shfl((u32)v, src, 64);
  u32 hi = __shfl((u32)(v >> 32), src, 64);
  return ((u64)hi << 32) | lo;
}
__device__ __forceinline__ u64 shfl_xor_u64(u64 v, int m) {
  u32 lo = __shfl_xor((u32)v, m, 64);
  u32 hi = __shfl_xor((u32)(v >> 32), m, 64);
  return ((u64)hi << 32) | lo;
}

// One 64-lane wave per anchor: rank = #{keys smaller}, then scatter
// decoded box + score into sorted position.
__global__ void __launch_bounds__(256) rank_kernel(const float* __restrict__ raw,
                                                   float4* __restrict__ sbox,
                                                   float* __restrict__ sscore) {
  #pragma clang fp contract(off)
  int tid = blockIdx.x * 256 + threadIdx.x;
  int row = tid >> 6, lane = tid & 63;
  if (row >= N_ANCH) return;
  float si = raw[4 * N_ANCH + row];
  u64 ki = sort_key(si, row);
  int cnt = 0;
  for (int j = lane; j < N_ANCH; j += 64) {
    float sj = raw[4 * N_ANCH + j];
    cnt += (sort_key(sj, j) < ki) ? 1 : 0;
  }
  #pragma unroll
  for (int d = 1; d < 64; d <<= 1) cnt += __shfl_xor(cnt, d, 64);
  if (lane == 0) {
    float cx = raw[row], cy = raw[N_ANCH + row];
    float w = raw[2 * N_ANCH + row], h = raw[3 * N_ANCH + row];
    float hw = w * 0.5f, hh = h * 0.5f;
    sbox[cnt] = make_float4(cx - hw, cy - hh, cx + hw, cy + hh);
    sscore[cnt] = si;
  }
}

// Suppression bitmask over sorted boxes: mask[i*CBLK+cb] bit jj set iff
// j = cb*64+jj satisfies j>i, j<N, iou(i,j) > 0.5.  Upper triangle only,
// and only blocks that contain at least one valid box (scores are sorted
// descending, so "first score of block >= THR" == "block has valid rows").
__global__ void __launch_bounds__(64) mask_kernel(const float4* __restrict__ sbox,
                                                  const float* __restrict__ sscore,
                                                  u64* __restrict__ mask) {
  #pragma clang fp contract(off)
  int cb = blockIdx.x, rb = blockIdx.y;
  if (cb < rb) return;                    // strictly-lower col blocks never read
  if (!(sscore[rb * 64] >= SCORE_THR)) return;  // row block fully invalid
  if (!(sscore[cb * 64] >= SCORE_THR)) return;  // col block fully invalid -> never read
  int t = threadIdx.x;
  __shared__ float4 cbox[64];
  __shared__ float carea[64];
  int j0 = cb * 64;
  int j = j0 + t;
  float4 bj = (j < N_ANCH) ? sbox[j] : make_float4(0.f, 0.f, 0.f, 0.f);
  cbox[t] = bj;
  carea[t] = (bj.z - bj.x) * (bj.w - bj.y);
  __syncthreads();
  int i = rb * 64 + t;
  if (i >= N_ANCH) return;
  float4 bi = sbox[i];
  float ai = (bi.z - bi.x) * (bi.w - bi.y);
  u64 word = 0;
  for (int jj = 0; jj < 64; ++jj) {
    int jg = j0 + jj;
    if (jg <= i || jg >= N_ANCH) continue;
    float4 bb = cbox[jj];
    float ltx = fmaxf(bi.x, bb.x), lty = fmaxf(bi.y, bb.y);
    float rbx = fminf(bi.z, bb.z), rby = fminf(bi.w, bb.w);
    float wx = fmaxf(rbx - ltx, 0.f), wy = fmaxf(rby - lty, 0.f);
    float inter = wx * wy;
    float uni = (ai + carea[jj]) - inter;      // same op order as reference
    float iou = inter / fmaxf(uni, 1e-9f);     // IEEE div, matches numpy
    if (iou > 0.5f) word |= (1ull << jj);
  }
  mask[(u64)i * CBLK + cb] = word;
}

// Single block, 256 threads (4 waves). Latency-minimized greedy NMS:
//  - validity ballots staged once in LDS
//  - removed word for block b computed by deferred-OR over the kept-row
//    list (parallel gather, <=3 independent loads/thread, one latency/block)
//  - intra-block scan: wave 0, diagonal mask words in registers, shfl chain
__global__ void __launch_bounds__(256) nms_kernel(const float4* __restrict__ sbox,
                                                  const float* __restrict__ sscore,
                                                  const u64* __restrict__ mask,
                                                  float* __restrict__ out) {
  __shared__ u64 valid[CBLK];
  __shared__ u64 keepw[CBLK];
  __shared__ u16 krow[8448];     // kept rows (sorted order), worst case all valid
  __shared__ u32 nkept;
  __shared__ u64 red[4];
  __shared__ int vb_sh;

  int t = threadIdx.x;
  int wave = t >> 6, lane = t & 63;

  if (t == 0) { nkept = 0; vb_sh = -1; }
  // stage validity ballots; zero keepw
  for (int b = wave; b < CBLK; b += 4) {
    int r = b * 64 + lane;
    float s = (r < N_ANCH) ? sscore[r] : -1.0f;
    u64 bal = __ballot(s >= SCORE_THR);
    if (lane == 0) { valid[b] = bal; keepw[b] = 0; }
  }
  __syncthreads();
  // valid blocks form a prefix (scores sorted desc): find last one
  if (t < CBLK) {
    if (valid[t] != 0 && (t == CBLK - 1 || valid[t + 1] == 0)) vb_sh = t;
  }
  __syncthreads();
  int VB = vb_sh;
  int nk = 0;

  for (int b = 0; b <= VB; ++b) {
    // --- parallel gather: removed word contribution from all kept rows so far
    u64 acc = 0;
    for (int i = t; i < nk; i += 256)
      acc |= mask[(u64)krow[i] * CBLK + b];
    // --- wave 0 concurrently gathers the diagonal mask words (registers)
    u64 mw = 0;
    if (wave == 0) {
      int r = b * 64 + lane;
      if (r < N_ANCH) mw = mask[(u64)r * CBLK + b];
    }
    // --- OR-reduce acc across 256 threads
    #pragma unroll
    for (int d = 1; d < 64; d <<= 1) acc |= shfl_xor_u64(acc, d);
    if (lane == 0) red[wave] = acc;
    __syncthreads();                               // (A)
    u64 R = red[0] | red[1] | red[2] | red[3];
    u64 act = valid[b] & ~R;
    if (act && wave == 0) {
      // greedy scan, redundantly on all 64 lanes of wave 0
      u64 a = act, kw = 0;
      while (a) {
        int l = (int)__builtin_ctzll(a);
        kw |= (1ull << l);
        a &= ~(1ull << l);
        u64 ml = shfl_u64(mw, l);
        a &= ~ml;                                  // ml only has bits > l
      }
      if (lane == 0) keepw[b] = kw;
      u32 nkold = nkept;
      if ((kw >> lane) & 1ull) {
        int pfx = __popcll(kw & ((1ull << lane) - 1ull));
        krow[nkold + pfx] = (u16)(b * 64 + lane);
      }
      if (lane == 0) nkept = nkold + (u32)__popcll(kw);
    }
    __syncthreads();                               // (B)
    nk = (int)nkept;
  }
  __syncthreads();

  // fused masked output write
  const float* sb = (const float*)sbox;
  for (int e = t; e < N_ANCH * 5; e += 256) {
    int r = e / 5, f = e - 5 * r;
    float v = 0.f;
    if ((keepw[r >> 6] >> (r & 63)) & 1ull) {
      v = (f == 4) ? sscore[r] : sb[r * 4 + f];
    }
    out[e] = v;
  }
}

extern "C" void kernel_launch(void* const* d_in, const int* in_sizes, int n_in,
                              void* d_out, int out_size, void* d_ws, size_t ws_size,
                              hipStream_t stream) {
  const float* raw = (const float*)d_in[0];
  float* out = (float*)d_out;
  char* ws = (char*)d_ws;
  // ws layout: sbox (8448*16 B) | sscore (8448*4 B) | mask (8400*132*8 B) ≈ 9.04 MB
  float4* sbox = (float4*)ws;
  float* sscore = (float*)(ws + 8448 * 16);
  u64* mask = (u64*)(ws + 8448 * 16 + 8448 * 4);

  rank_kernel<<<2100, 256, 0, stream>>>(raw, sbox, sscore);
  mask_kernel<<<dim3(CBLK, CBLK), 64, 0, stream>>>(sbox, sscore, mask);
  nms_kernel<<<1, 256, 0, stream>>>(sbox, sscore, mask, out);
}